// Round 13
// baseline (219.138 us; speedup 1.0000x reference)
//
#include <hip/hip_runtime.h>
#include <hip/hip_cooperative_groups.h>
#include <cstdint>

namespace cg = cooperative_groups;

// Problem constants (from reference)
#define N_NODES 100000
#define N_EDGES 1600000
#define D_IN    128
#define D_H     64
#define D_OUT   16
#define M_TILES 6250   // N_NODES / 16

// Bucket sort parameters (1024 buckets == cooperative grid size)
#define NBKT   1024
#define NPB    98      // nodes per bucket; 1024*98 = 100352 >= N
#define BCAP   2048    // per-bucket capacity (mean ~1568, sd ~40 -> +12 sigma)
#define EPT    8       // edges per thread in bin phase
#define TILE_E 2048    // 256 threads * 8 edges
#define NTILES 782     // ceil(1600000/2048)
#define GRID_B 1024    // cooperative grid: 4 blocks/CU x 256 CUs

typedef __attribute__((ext_vector_type(8))) short short8;
typedef __attribute__((ext_vector_type(4))) float floatx4;

static __device__ __forceinline__ unsigned short f2bf(float f) {
    unsigned int u = __float_as_uint(f);
    u = u + 0x7FFFu + ((u >> 16) & 1u);
    return (unsigned short)(u >> 16);
}
static __device__ __forceinline__ float bf2f(unsigned short h) {
    return __uint_as_float(((unsigned int)h) << 16);
}

// ---------------------------------------------------------------------------
// Workspace layout (bytes):
//   cursors : NBKT int          @ 0         (4096)
//   offsets : N+1 int           @ 4096
//   dinv    : N float           @ 404224
//   srcs    : E+16 int (CSR)    @ 804224    (ends 7204288; 16-entry zero pad)
//   hs      : N*64 bf16 bits    @ 7204352
//   h2s     : N*16 float        @ 20004480
//   region  : NBKT*BCAP int     @ 26404480  (ends 34793088)
//   w1hi    : 8192 ushort       @ 34793088  (fragment-ordered W1 hi)
//   w1lo    : 8192 ushort       @ 34809472  (fragment-ordered W1 lo)
// total ~34.9 MB
// ---------------------------------------------------------------------------

// LDS union — max member ~10 KB (build). gemm1 no longer stages W1 in LDS
// (R12 failure: 32 KB union pushed co-residency below 4 blocks/CU and the
// unchecked cooperative launch silently failed).
union SMem {
    struct { int hcnt[NBKT]; int hbase[NBKT]; } bin;                       // 8 KB
    struct { int lhist[NPB]; int lscan[NPB + 1]; int sbuf[256]; int red[4];
             int srt[BCAP]; } bld;                                         // ~10 KB
    float rbuf[256];                                                       // 1 KB
};

__global__ __launch_bounds__(256, 4) void mega_kernel(
        const float* __restrict__ x,
        const int* __restrict__ esrc, const int* __restrict__ edst,
        const float* __restrict__ W1, const float* __restrict__ b1,
        const float* __restrict__ W2, const float* __restrict__ b2,
        float* __restrict__ out,
        int* __restrict__ cursors, int* __restrict__ offsets,
        float* __restrict__ dinv, int* __restrict__ srcs,
        unsigned short* __restrict__ hs, float* __restrict__ h2s,
        int* __restrict__ region,
        unsigned short* __restrict__ w1hi, unsigned short* __restrict__ w1lo) {
    cg::grid_group grid = cg::this_grid();
    __shared__ SMem sm;
    const int t = threadIdx.x;
    const int gtid = blockIdx.x * 256 + t;

    // ---- Phase 0: zero cursors + srcs pad; stage W1 hi/lo fragments ----
    if (gtid < NBKT) cursors[gtid] = 0;
    if (gtid < 16) srcs[N_EDGES + gtid] = 0;
    if (gtid < 8192) {
        int e = gtid;
        int j    = e & 7;
        int lane = (e >> 3) & 63;
        int pair = e >> 9;          // kc*4 + nt
        int kc   = pair >> 2;
        int nt   = pair & 3;
        int k = kc * 32 + (lane >> 4) * 8 + j;
        int n = nt * 16 + (lane & 15);
        float w = W1[k * D_H + n];
        unsigned short hi = f2bf(w);
        w1hi[e] = hi;
        w1lo[e] = f2bf(w - bf2f(hi));
    }
    grid.sync();

    // ---- Phase 1: bin (one 2048-edge tile per block) ----
    {
        int tile = blockIdx.x;
        if (tile < NTILES) {
            for (int i = t; i < NBKT; i += 256) sm.bin.hcnt[i] = 0;
            __syncthreads();
            int e0 = tile * TILE_E + t * EPT;
            int pk[EPT], bk[EPT], rk[EPT];
            bool full = (e0 + EPT <= N_EDGES);   // N_EDGES % 8 == 0
            if (full) {
                const int4* dp = (const int4*)(edst + e0);
                const int4* sp = (const int4*)(esrc + e0);
                int dv[EPT], sv[EPT];
                #pragma unroll
                for (int q = 0; q < EPT / 4; ++q) {
                    int4 d4 = dp[q]; int4 s4 = sp[q];
                    dv[4*q+0]=d4.x; dv[4*q+1]=d4.y; dv[4*q+2]=d4.z; dv[4*q+3]=d4.w;
                    sv[4*q+0]=s4.x; sv[4*q+1]=s4.y; sv[4*q+2]=s4.z; sv[4*q+3]=s4.w;
                }
                #pragma unroll
                for (int k = 0; k < EPT; ++k) {
                    int d = dv[k];
                    int b = d / NPB;               // magic-mul
                    bk[k] = b;
                    pk[k] = ((d - b * NPB) << 17) | sv[k];
                    rk[k] = atomicAdd(&sm.bin.hcnt[b], 1);
                }
            }
            __syncthreads();
            for (int i = t; i < NBKT; i += 256) {
                int c = sm.bin.hcnt[i];
                if (c > 0) sm.bin.hbase[i] = atomicAdd(&cursors[i], c);
            }
            __syncthreads();
            if (full) {
                #pragma unroll
                for (int k = 0; k < EPT; ++k)
                    region[bk[k] * BCAP + sm.bin.hbase[bk[k]] + rk[k]] = pk[k];
            }
        }
    }
    grid.sync();

    // ---- Phase 2: build (one block per bucket) ----
    {
        int b = blockIdx.x;
        int p = 0;
        #pragma unroll
        for (int j = 0; j < 4; ++j) {
            int i = t + 256 * j;
            int cv = cursors[i];
            p += (i < b) ? cv : 0;
        }
        int lane = t & 63, wid = t >> 6;
        #pragma unroll
        for (int off = 32; off > 0; off >>= 1) p += __shfl_down(p, off);
        if (lane == 0) sm.bld.red[wid] = p;
        __syncthreads();
        int base = sm.bld.red[0] + sm.bld.red[1] + sm.bld.red[2] + sm.bld.red[3];
        int cnt = cursors[b];
        const int* reg = region + b * BCAP;

        for (int i = t; i < NPB; i += 256) sm.bld.lhist[i] = 0;
        __syncthreads();
        for (int i = t; i < cnt; i += 256)
            atomicAdd(&sm.bld.lhist[reg[i] >> 17], 1);
        __syncthreads();
        int v = (t < NPB) ? sm.bld.lhist[t] : 0;
        sm.bld.sbuf[t] = v;
        __syncthreads();
        for (int off = 1; off < 256; off <<= 1) {
            int u = (t >= off) ? sm.bld.sbuf[t - off] : 0;
            __syncthreads();
            sm.bld.sbuf[t] += u;
            __syncthreads();
        }
        int incl = sm.bld.sbuf[t];
        if (t < NPB) sm.bld.lscan[t] = incl - v;
        if (t == NPB - 1) sm.bld.lscan[NPB] = incl;
        __syncthreads();
        if (t < NPB) sm.bld.lhist[t] = incl - v;    // running cursor
        __syncthreads();

        int node0 = b * NPB;
        int nlim = N_NODES - node0;
        if (nlim > NPB) nlim = NPB;
        if (t < nlim) {
            offsets[node0 + t] = base + sm.bld.lscan[t];
            int c = sm.bld.lscan[t + 1] - sm.bld.lscan[t];
            dinv[node0 + t] = rsqrtf((float)c + 1.0f);   // +1 self loop
        }
        if (b == (N_NODES - 1) / NPB && t == 0) offsets[N_NODES] = base + cnt;

        for (int i = t; i < cnt; i += 256) {
            int pk2 = reg[i];
            int pos = atomicAdd(&sm.bld.lhist[pk2 >> 17], 1);
            sm.bld.srt[pos] = pk2 & 0x1FFFF;
        }
        __syncthreads();
        for (int i = t; i < cnt; i += 256) srcs[base + i] = sm.bld.srt[i];
    }
    grid.sync();

    // ---- Phase 3: gemm1 (MFMA bf16x2; W1 fragments from global, L1-hot) ----
    {
        int wid  = t >> 6;
        int lane = t & 63;
        int quad = lane >> 4;
        int m    = lane & 15;

        for (int tile = blockIdx.x * 4 + wid; tile < M_TILES; tile += gridDim.x * 4) {
            int mbase = tile * 16;
            const float* xr = x + (size_t)(mbase + m) * D_IN + quad * 8;
            short8 ahi[4], alo[4];
            #pragma unroll
            for (int kc = 0; kc < 4; ++kc) {
                floatx4 v0 = *(const floatx4*)(xr + kc * 32);
                floatx4 v1 = *(const floatx4*)(xr + kc * 32 + 4);
                float f[8] = {v0.x, v0.y, v0.z, v0.w, v1.x, v1.y, v1.z, v1.w};
                #pragma unroll
                for (int j = 0; j < 8; ++j) {
                    unsigned short hi = f2bf(f[j]);
                    ahi[kc][j] = (short)hi;
                    alo[kc][j] = (short)f2bf(f[j] - bf2f(hi));
                }
            }
            floatx4 acc[4] = {{0.f,0.f,0.f,0.f},{0.f,0.f,0.f,0.f},{0.f,0.f,0.f,0.f},{0.f,0.f,0.f,0.f}};
            #pragma unroll
            for (int kc = 0; kc < 4; ++kc) {
                #pragma unroll
                for (int nt = 0; nt < 4; ++nt) {
                    int fo = ((kc * 4 + nt) * 64 + lane) * 8;
                    short8 bhi = *(const short8*)&w1hi[fo];   // coalesced 16B/lane
                    short8 blo = *(const short8*)&w1lo[fo];
                    acc[nt] = __builtin_amdgcn_mfma_f32_16x16x32_bf16(ahi[kc], bhi, acc[nt], 0, 0, 0);
                    acc[nt] = __builtin_amdgcn_mfma_f32_16x16x32_bf16(ahi[kc], blo, acc[nt], 0, 0, 0);
                    acc[nt] = __builtin_amdgcn_mfma_f32_16x16x32_bf16(alo[kc], bhi, acc[nt], 0, 0, 0);
                }
            }
            float dv[4];
            #pragma unroll
            for (int r = 0; r < 4; ++r) dv[r] = dinv[mbase + quad * 4 + r];
            #pragma unroll
            for (int nt = 0; nt < 4; ++nt) {
                int col = nt * 16 + m;
                #pragma unroll
                for (int r = 0; r < 4; ++r)
                    hs[(mbase + quad * 4 + r) * D_H + col] = f2bf(acc[nt][r] * dv[r]);
            }
        }
    }
    grid.sync();

    // ---- Phase 4: agg1 + ReLU + layer-2 projection (scalar-path gathers) ----
    {
        int wid  = t >> 6;
        int lane = t & 63;
        int wave = (blockIdx.x * 256 + t) >> 6;
        const int nwaves = gridDim.x * 4;
        int q = lane >> 4;
        int c = lane & 15;
        float w2c[16];
        #pragma unroll
        for (int j = 0; j < 16; ++j) w2c[j] = W2[(q * 16 + j) * D_OUT + c];
        float bias = b1[lane];
        float* myr = &sm.rbuf[wid * 64];

        for (int node = wave; node < N_NODES; node += nwaves) {
            int beg = __builtin_amdgcn_readfirstlane(offsets[node]);
            int end = __builtin_amdgcn_readfirstlane(offsets[node + 1]);
            float acc = bf2f(hs[node * D_H + lane]);  // self loop
            for (int e = beg; e < end; e += 16) {
                int rem = end - e;
                const int* ep = srcs + e;
                int jj[16];
                #pragma unroll
                for (int k = 0; k < 16; ++k)
                    jj[k] = __builtin_amdgcn_readfirstlane(ep[k]);
                float vv[16];
                #pragma unroll
                for (int k = 0; k < 16; ++k) {
                    const unsigned short* hp = hs + (size_t)jj[k] * D_H;
                    vv[k] = bf2f(hp[lane]);
                }
                #pragma unroll
                for (int k = 0; k < 16; ++k) {
                    float m = (k < rem) ? 1.0f : 0.0f;
                    acc = fmaf(vv[k], m, acc);
                }
            }
            float dv = dinv[node];
            float r = fmaxf(acc * dv + bias, 0.f);
            myr[lane] = r;                       // wave-synchronous LDS transpose
            float part = 0.f;
            #pragma unroll
            for (int j = 0; j < 16; ++j) part += myr[q * 16 + j] * w2c[j];
            part += __shfl_xor(part, 16);
            part += __shfl_xor(part, 32);
            if (lane < 16) h2s[node * D_OUT + lane] = part * dv;
        }
    }
    grid.sync();

    // ---- Phase 5: agg2 ----
    {
        int col = t & 15;
        int nidx = (blockIdx.x * 256 + t) >> 4;
        const int stride = (gridDim.x * 256) >> 4;
        for (int node = nidx; node < N_NODES; node += stride) {
            int beg = offsets[node], end = offsets[node + 1];
            float acc = h2s[node * D_OUT + col];  // self loop
            for (int e = beg; e < end; e += 16) {
                int rem = end - e;
                const int* ep = srcs + e;
                int jj[16];
                #pragma unroll
                for (int k = 0; k < 16; ++k) jj[k] = ep[k];
                float vv[16];
                #pragma unroll
                for (int k = 0; k < 16; ++k) vv[k] = h2s[jj[k] * D_OUT + col];
                #pragma unroll
                for (int k = 0; k < 16; ++k) {
                    float m = (k < rem) ? 1.0f : 0.0f;
                    acc = fmaf(vv[k], m, acc);
                }
            }
            out[node * D_OUT + col] = acc * dinv[node] + b2[col];
        }
    }
}

// ======================= Fallback path (R11, proven 206 us) ==================

__global__ __launch_bounds__(1024) void fb_zero(int* __restrict__ cursors,
                                                int* __restrict__ srcs) {
    cursors[threadIdx.x] = 0;
    if (threadIdx.x < 16) srcs[N_EDGES + threadIdx.x] = 0;
}

__global__ __launch_bounds__(256) void fb_bin(const int* __restrict__ esrc,
                                              const int* __restrict__ edst,
                                              int* __restrict__ cursors,
                                              int* __restrict__ region) {
    __shared__ int hcnt[NBKT];
    __shared__ int hbase[NBKT];
    const int t = threadIdx.x;
    int tile = blockIdx.x;
    if (tile >= NTILES) return;
    for (int i = t; i < NBKT; i += 256) hcnt[i] = 0;
    __syncthreads();
    int e0 = tile * TILE_E + t * EPT;
    int pk[EPT], bk[EPT], rk[EPT];
    bool full = (e0 + EPT <= N_EDGES);
    if (full) {
        const int4* dp = (const int4*)(edst + e0);
        const int4* sp = (const int4*)(esrc + e0);
        int dv[EPT], sv[EPT];
        #pragma unroll
        for (int q = 0; q < EPT / 4; ++q) {
            int4 d4 = dp[q]; int4 s4 = sp[q];
            dv[4*q+0]=d4.x; dv[4*q+1]=d4.y; dv[4*q+2]=d4.z; dv[4*q+3]=d4.w;
            sv[4*q+0]=s4.x; sv[4*q+1]=s4.y; sv[4*q+2]=s4.z; sv[4*q+3]=s4.w;
        }
        #pragma unroll
        for (int k = 0; k < EPT; ++k) {
            int d = dv[k];
            int b = d / NPB;
            bk[k] = b;
            pk[k] = ((d - b * NPB) << 17) | sv[k];
            rk[k] = atomicAdd(&hcnt[b], 1);
        }
    }
    __syncthreads();
    for (int i = t; i < NBKT; i += 256) {
        int c = hcnt[i];
        if (c > 0) hbase[i] = atomicAdd(&cursors[i], c);
    }
    __syncthreads();
    if (full) {
        #pragma unroll
        for (int k = 0; k < EPT; ++k)
            region[bk[k] * BCAP + hbase[bk[k]] + rk[k]] = pk[k];
    }
}

__global__ __launch_bounds__(256) void fb_build(const int* __restrict__ cursors,
                                                const int* __restrict__ region,
                                                int* __restrict__ offsets,
                                                float* __restrict__ dinv,
                                                int* __restrict__ srcs) {
    __shared__ int lhist[NPB];
    __shared__ int lscan[NPB + 1];
    __shared__ int sbuf[256];
    __shared__ int srt[BCAP];
    __shared__ int red[4];
    int b = blockIdx.x;
    int t = threadIdx.x;
    int p = 0;
    #pragma unroll
    for (int j = 0; j < 4; ++j) {
        int i = t + 256 * j;
        int cv = cursors[i];
        p += (i < b) ? cv : 0;
    }
    int lane = t & 63, wid = t >> 6;
    #pragma unroll
    for (int off = 32; off > 0; off >>= 1) p += __shfl_down(p, off);
    if (lane == 0) red[wid] = p;
    __syncthreads();
    int base = red[0] + red[1] + red[2] + red[3];
    int cnt = cursors[b];
    const int* reg = region + b * BCAP;

    for (int i = t; i < NPB; i += 256) lhist[i] = 0;
    __syncthreads();
    for (int i = t; i < cnt; i += 256) atomicAdd(&lhist[reg[i] >> 17], 1);
    __syncthreads();
    int v = (t < NPB) ? lhist[t] : 0;
    sbuf[t] = v;
    __syncthreads();
    for (int off = 1; off < 256; off <<= 1) {
        int u = (t >= off) ? sbuf[t - off] : 0;
        __syncthreads();
        sbuf[t] += u;
        __syncthreads();
    }
    int incl = sbuf[t];
    if (t < NPB) lscan[t] = incl - v;
    if (t == NPB - 1) lscan[NPB] = incl;
    __syncthreads();
    if (t < NPB) lhist[t] = incl - v;
    __syncthreads();

    int node0 = b * NPB;
    int nlim = N_NODES - node0;
    if (nlim > NPB) nlim = NPB;
    if (t < nlim) {
        offsets[node0 + t] = base + lscan[t];
        int c = lscan[t + 1] - lscan[t];
        dinv[node0 + t] = rsqrtf((float)c + 1.0f);
    }
    if (b == (N_NODES - 1) / NPB && t == 0) offsets[N_NODES] = base + cnt;

    for (int i = t; i < cnt; i += 256) {
        int pk2 = reg[i];
        int pos = atomicAdd(&lhist[pk2 >> 17], 1);
        srt[pos] = pk2 & 0x1FFFF;
    }
    __syncthreads();
    for (int i = t; i < cnt; i += 256) srcs[base + i] = srt[i];
}

__global__ __launch_bounds__(256) void fb_gemm1(const float* __restrict__ x,
                                                const float* __restrict__ W1,
                                                const float* __restrict__ dinv,
                                                unsigned short* __restrict__ hs) {
    __shared__ unsigned short bhi_lds[8192];
    __shared__ unsigned short blo_lds[8192];
    for (int e = threadIdx.x; e < 8192; e += 256) {
        int j    = e & 7;
        int lane = (e >> 3) & 63;
        int pair = e >> 9;
        int kc   = pair >> 2;
        int nt   = pair & 3;
        int k = kc * 32 + (lane >> 4) * 8 + j;
        int n = nt * 16 + (lane & 15);
        float w = W1[k * D_H + n];
        unsigned short hi = f2bf(w);
        bhi_lds[e] = hi;
        blo_lds[e] = f2bf(w - bf2f(hi));
    }
    __syncthreads();
    int wid  = threadIdx.x >> 6;
    int lane = threadIdx.x & 63;
    int quad = lane >> 4;
    int m    = lane & 15;
    int tile = blockIdx.x * 4 + wid;
    if (tile >= M_TILES) return;
    int mbase = tile * 16;
    const float* xr = x + (size_t)(mbase + m) * D_IN + quad * 8;
    short8 ahi[4], alo[4];
    #pragma unroll
    for (int kc = 0; kc < 4; ++kc) {
        floatx4 v0 = *(const floatx4*)(xr + kc * 32);
        floatx4 v1 = *(const floatx4*)(xr + kc * 32 + 4);
        float f[8] = {v0.x, v0.y, v0.z, v0.w, v1.x, v1.y, v1.z, v1.w};
        #pragma unroll
        for (int j = 0; j < 8; ++j) {
            unsigned short hi = f2bf(f[j]);
            ahi[kc][j] = (short)hi;
            alo[kc][j] = (short)f2bf(f[j] - bf2f(hi));
        }
    }
    floatx4 acc[4] = {{0.f,0.f,0.f,0.f},{0.f,0.f,0.f,0.f},{0.f,0.f,0.f,0.f},{0.f,0.f,0.f,0.f}};
    #pragma unroll
    for (int kc = 0; kc < 4; ++kc) {
        #pragma unroll
        for (int nt = 0; nt < 4; ++nt) {
            int fo = ((kc * 4 + nt) * 64 + lane) * 8;
            short8 bhi = *(const short8*)&bhi_lds[fo];
            short8 blo = *(const short8*)&blo_lds[fo];
            acc[nt] = __builtin_amdgcn_mfma_f32_16x16x32_bf16(ahi[kc], bhi, acc[nt], 0, 0, 0);
            acc[nt] = __builtin_amdgcn_mfma_f32_16x16x32_bf16(ahi[kc], blo, acc[nt], 0, 0, 0);
            acc[nt] = __builtin_amdgcn_mfma_f32_16x16x32_bf16(alo[kc], bhi, acc[nt], 0, 0, 0);
        }
    }
    float dv[4];
    #pragma unroll
    for (int r = 0; r < 4; ++r) dv[r] = dinv[mbase + quad * 4 + r];
    #pragma unroll
    for (int nt = 0; nt < 4; ++nt) {
        int col = nt * 16 + m;
        #pragma unroll
        for (int r = 0; r < 4; ++r)
            hs[(mbase + quad * 4 + r) * D_H + col] = f2bf(acc[nt][r] * dv[r]);
    }
}

__global__ __launch_bounds__(256) void fb_agg1(const unsigned short* __restrict__ hs,
                                               const int* __restrict__ offsets,
                                               const int* __restrict__ srcs,
                                               const float* __restrict__ dinv,
                                               const float* __restrict__ b1,
                                               const float* __restrict__ W2,
                                               float* __restrict__ h2s) {
    __shared__ float rbuf[256];
    int wid  = threadIdx.x >> 6;
    int lane = threadIdx.x & 63;
    int wave = (blockIdx.x * blockDim.x + threadIdx.x) >> 6;
    int nwaves = (gridDim.x * blockDim.x) >> 6;
    int q = lane >> 4;
    int c = lane & 15;
    float w2c[16];
    #pragma unroll
    for (int j = 0; j < 16; ++j) w2c[j] = W2[(q * 16 + j) * D_OUT + c];
    float bias = b1[lane];
    float* myr = &rbuf[wid * 64];
    for (int node = wave; node < N_NODES; node += nwaves) {
        int beg = __builtin_amdgcn_readfirstlane(offsets[node]);
        int end = __builtin_amdgcn_readfirstlane(offsets[node + 1]);
        float acc = bf2f(hs[node * D_H + lane]);
        for (int e = beg; e < end; e += 16) {
            int rem = end - e;
            const int* ep = srcs + e;
            int jj[16];
            #pragma unroll
            for (int k = 0; k < 16; ++k) jj[k] = __builtin_amdgcn_readfirstlane(ep[k]);
            float vv[16];
            #pragma unroll
            for (int k = 0; k < 16; ++k) {
                const unsigned short* hp = hs + (size_t)jj[k] * D_H;
                vv[k] = bf2f(hp[lane]);
            }
            #pragma unroll
            for (int k = 0; k < 16; ++k) {
                float m = (k < rem) ? 1.0f : 0.0f;
                acc = fmaf(vv[k], m, acc);
            }
        }
        float dv = dinv[node];
        float r = fmaxf(acc * dv + bias, 0.f);
        myr[lane] = r;
        float part = 0.f;
        #pragma unroll
        for (int j = 0; j < 16; ++j) part += myr[q * 16 + j] * w2c[j];
        part += __shfl_xor(part, 16);
        part += __shfl_xor(part, 32);
        if (lane < 16) h2s[node * D_OUT + lane] = part * dv;
    }
}

__global__ __launch_bounds__(256) void fb_agg2(const float* __restrict__ h2s,
                                               const int* __restrict__ offsets,
                                               const int* __restrict__ srcs,
                                               const float* __restrict__ dinv,
                                               const float* __restrict__ b2,
                                               float* __restrict__ out) {
    int col = threadIdx.x & 15;
    int nidx = (blockIdx.x * blockDim.x + threadIdx.x) >> 4;
    int stride = (gridDim.x * blockDim.x) >> 4;
    for (int node = nidx; node < N_NODES; node += stride) {
        int beg = offsets[node], end = offsets[node + 1];
        float acc = h2s[node * D_OUT + col];
        for (int e = beg; e < end; e += 16) {
            int rem = end - e;
            const int* ep = srcs + e;
            int jj[16];
            #pragma unroll
            for (int k = 0; k < 16; ++k) jj[k] = ep[k];
            float vv[16];
            #pragma unroll
            for (int k = 0; k < 16; ++k) vv[k] = h2s[jj[k] * D_OUT + col];
            #pragma unroll
            for (int k = 0; k < 16; ++k) {
                float m = (k < rem) ? 1.0f : 0.0f;
                acc = fmaf(vv[k], m, acc);
            }
        }
        out[node * D_OUT + col] = acc * dinv[node] + b2[col];
    }
}

extern "C" void kernel_launch(void* const* d_in, const int* in_sizes, int n_in,
                              void* d_out, int out_size, void* d_ws, size_t ws_size,
                              hipStream_t stream) {
    const float* x  = (const float*)d_in[0];
    const int*   ei = (const int*)d_in[1];
    const float* W1 = (const float*)d_in[2];
    const float* b1 = (const float*)d_in[3];
    const float* W2 = (const float*)d_in[4];
    const float* b2 = (const float*)d_in[5];
    float* out = (float*)d_out;

    const int* esrc = ei;             // edge_index[0]
    const int* edst = ei + N_EDGES;   // edge_index[1]

    char* w = (char*)d_ws;
    int*   cursors  = (int*)(w + 0);
    int*   offsets  = (int*)(w + 4096);
    float* dinv     = (float*)(w + 404224);
    int*   srcs     = (int*)(w + 804224);
    unsigned short* hs = (unsigned short*)(w + 7204352);
    float* h2s      = (float*)(w + 20004480);
    int*   region   = (int*)(w + 26404480);
    unsigned short* w1hi = (unsigned short*)(w + 34793088);
    unsigned short* w1lo = (unsigned short*)(w + 34809472);

    // Guard: cooperative grid of 1024 requires >= 4 co-resident blocks/CU.
    int maxB = 0;
    hipError_t oerr = hipOccupancyMaxActiveBlocksPerMultiprocessor(
        &maxB, (const void*)mega_kernel, 256, 0);
    bool coop_ok = (oerr == hipSuccess) && (maxB >= 4);

    if (coop_ok) {
        void* args[] = { (void*)&x, (void*)&esrc, (void*)&edst, (void*)&W1, (void*)&b1,
                         (void*)&W2, (void*)&b2, (void*)&out,
                         (void*)&cursors, (void*)&offsets, (void*)&dinv, (void*)&srcs,
                         (void*)&hs, (void*)&h2s, (void*)&region,
                         (void*)&w1hi, (void*)&w1lo };
        hipError_t lerr = hipLaunchCooperativeKernel((const void*)mega_kernel,
                                                     dim3(GRID_B), dim3(256),
                                                     args, 0, stream);
        if (lerr == hipSuccess) return;
        coop_ok = false;   // fall through to the proven multi-dispatch path
    }

    fb_zero<<<1, 1024, 0, stream>>>(cursors, srcs);
    fb_bin<<<NTILES, 256, 0, stream>>>(esrc, edst, cursors, region);
    fb_build<<<NBKT, 256, 0, stream>>>(cursors, region, offsets, dinv, srcs);
    fb_gemm1<<<(M_TILES + 3) / 4, 256, 0, stream>>>(x, W1, dinv, hs);
    fb_agg1<<<6250, 256, 0, stream>>>(hs, offsets, srcs, dinv, b1, W2, h2s);
    fb_agg2<<<6250, 256, 0, stream>>>(h2s, offsets, srcs, dinv, b2, out);
}